// Round 1
// 1017.609 us; speedup vs baseline: 1.2168x; 1.2168x over previous
//
#include <hip/hip_runtime.h>

// ---------- helpers ----------
typedef __attribute__((ext_vector_type(4))) float f4;
typedef __attribute__((ext_vector_type(8))) short s8;

__device__ inline float b2f(unsigned int u) {
    unsigned int v = u << 16;
    float f;
    __builtin_memcpy(&f, &v, 4);
    return f;
}
__device__ inline unsigned short f2b(float f) {
    unsigned int u;
    __builtin_memcpy(&u, &f, 4);
    unsigned int r = u + 0x7fffu + ((u >> 16) & 1u);
    return (unsigned short)(r >> 16);
}
__device__ inline void async16(const void* g, void* l) {
    __builtin_amdgcn_global_load_lds(
        (const __attribute__((address_space(1))) unsigned int*)g,
        (__attribute__((address_space(3))) unsigned int*)l, 16, 0, 0);
}

#define B_ROWS 8192
#define DIN 1024
#define DH 2048
#define DOUT 1024
#define NE 8
#define NCAT 16384   // NE * DH

// ---------- dtype detection: flag=1 if inputs are fp32, 0 if bf16 ----------
__global__ __launch_bounds__(64) void detect_dtype(const unsigned short* __restrict__ p, int* __restrict__ flag)
{
    const int lane = threadIdx.x;
    int sane = 0;
    for (int i = lane; i < 4096; i += 64) {
        const float a = fabsf(b2f(p[i]));
        if (a > 1e-30f && a < 1e3f) sane++;
    }
    for (int off = 32; off; off >>= 1) sane += __shfl_xor(sane, off, 64);
    if (lane == 0) *flag = (sane < 3600) ? 1 : 0;
}

// ---------- normalize any input tensor to bf16 ----------
__global__ __launch_bounds__(256) void normalize_kernel(const void* __restrict__ src,
                                                        unsigned short* __restrict__ dst,
                                                        const int* __restrict__ flag, int n)
{
    const int i = blockIdx.x * 256 + threadIdx.x;
    if (i >= n) return;
    if (*flag) dst[i] = f2b(((const float*)src)[i]);
    else       dst[i] = ((const unsigned short*)src)[i];
}

// ---------- gating ----------
__global__ __launch_bounds__(256) void gating_kernel(
    const unsigned short* __restrict__ x, const unsigned short* __restrict__ gum,
    const unsigned short* __restrict__ gw, const unsigned short* __restrict__ gb,
    float* __restrict__ probs, float* __restrict__ partials)
{
    const int t = threadIdx.x, wave = t >> 6, lane = t & 63;
    float sp = 0.f, sr = 0.f;
    const int base = blockIdx.x * 32 + wave * 8;
    for (int rr = 0; rr < 8; rr++) {
        const int b = base + rr;
        float acc[8];
#pragma unroll
        for (int e = 0; e < 8; e++) acc[e] = 0.f;
        for (int kk = 0; kk < 16; kk++) {
            const int k = kk * 64 + lane;
            const float xv = b2f(x[(size_t)b * DIN + k]);
            const uint4 wv = *(const uint4*)(gw + (size_t)k * 8);
            acc[0] += xv * b2f(wv.x & 0xffffu); acc[1] += xv * b2f(wv.x >> 16);
            acc[2] += xv * b2f(wv.y & 0xffffu); acc[3] += xv * b2f(wv.y >> 16);
            acc[4] += xv * b2f(wv.z & 0xffffu); acc[5] += xv * b2f(wv.z >> 16);
            acc[6] += xv * b2f(wv.w & 0xffffu); acc[7] += xv * b2f(wv.w >> 16);
        }
#pragma unroll
        for (int e = 0; e < 8; e++)
            for (int off = 32; off; off >>= 1) acc[e] += __shfl_xor(acc[e], off, 64);
        float lg[8], p1[8], p2[8];
        float m1 = -1e30f, m2 = -1e30f;
#pragma unroll
        for (int e = 0; e < 8; e++) {
            lg[e] = acc[e] + b2f(gb[e]);
            p1[e] = (lg[e] + b2f(gum[(size_t)b * 8 + e])) * 1.25f;  // 1/tau
            p2[e] = lg[e] * 1.25f;
            m1 = fmaxf(m1, p1[e]); m2 = fmaxf(m2, p2[e]);
        }
        float s1 = 0.f, s2 = 0.f;
#pragma unroll
        for (int e = 0; e < 8; e++) {
            p1[e] = expf(p1[e] - m1); s1 += p1[e];
            p2[e] = expf(p2[e] - m2); s2 += p2[e];
        }
        const float i1 = 1.f / s1, i2 = 1.f / s2;
        if (lane < 8) {
            const float pv = p1[lane] * i1;
            probs[(size_t)b * 8 + lane] = pv;
            sp += pv;
            sr += p2[lane] * i2;
        }
    }
    __shared__ float red[4][16];
    if (lane < 8) { red[wave][lane] = sp; red[wave][8 + lane] = sr; }
    __syncthreads();
    if (t < 16)
        partials[blockIdx.x * 16 + t] = red[0][t] + red[1][t] + red[2][t] + red[3][t];
}

// ---------- aux loss finalize (dtype-branched output) ----------
__global__ void aux_finalize(const float* __restrict__ partials, void* __restrict__ outp,
                             const int* __restrict__ flag)
{
    __shared__ float fin[16];
    const int t = threadIdx.x;
    if (t < 16) {
        float s = 0.f;
        for (int i = 0; i < 256; i++) s += partials[i * 16 + t];
        fin[t] = s;
    }
    __syncthreads();
    if (t == 0) {
        float ld[8], im[8];
        for (int e = 0; e < 8; e++) { ld[e] = fin[e] / 8192.f; im[e] = fin[8 + e] / 8192.f; }
        float mi = 0.f, ml = 0.f;
        for (int e = 0; e < 8; e++) { mi += im[e]; ml += ld[e]; }
        mi *= 0.125f; ml *= 0.125f;
        float vi = 0.f, vl = 0.f, sw = 0.f;
        for (int e = 0; e < 8; e++) {
            vi += (im[e] - mi) * (im[e] - mi);
            vl += (ld[e] - ml) * (ld[e] - ml);
            sw += im[e] * ld[e];
        }
        const float cvi = sqrtf(vi / 7.f) / (mi + 1e-8f);
        const float cvl = sqrtf(vl / 7.f) / (ml + 1e-8f);
        const float aux = (8.f * sw + cvi + cvl) * 0.05f;
        if (*flag) ((float*)outp)[8388608] = aux;
        else       ((unsigned short*)outp)[8388608] = f2b(aux);
    }
}

// ---------- batched transpose+cvt: per z: src[z][R][C] -> out[z-block][C][R] ----------
__global__ __launch_bounds__(256) void transpose_cvt(
    const void* __restrict__ src, unsigned short* __restrict__ out,
    int R, int C, int ldOut, size_t outEStride, const int* __restrict__ flag)
{
    __shared__ unsigned short tile[64][65];
    const int e = blockIdx.z;
    const size_t eoff = (size_t)e * R * C;
    unsigned short* op = out + (size_t)e * outEStride;
    const int fl = *flag;
    const int tx = threadIdx.x, ty = threadIdx.y;
    const int r0 = blockIdx.y * 64, c0 = blockIdx.x * 64;
    if (fl) {
        const float* in = (const float*)src + eoff;
#pragma unroll
        for (int i = 0; i < 16; i++) {
            const int r = ty + i * 4;
            tile[r][tx] = f2b(in[(size_t)(r0 + r) * C + c0 + tx]);
        }
    } else {
        const unsigned short* in = (const unsigned short*)src + eoff;
#pragma unroll
        for (int i = 0; i < 16; i++) {
            const int r = ty + i * 4;
            tile[r][tx] = in[(size_t)(r0 + r) * C + c0 + tx];
        }
    }
    __syncthreads();
#pragma unroll
    for (int i = 0; i < 16; i++) {
        const int c = ty + i * 4;
        op[(size_t)(c0 + c) * ldOut + r0 + tx] = tile[tx][c];
    }
}

// ---------- GEMM1: Hcat[m, n] = bf16( relu(x@W1cat + b1cat[n]) * probs[m, n>>11] ) ----------
// 2-phase prefetch: stage(k+1) issued before compute(k); ONE barrier per K-step.
__global__ __launch_bounds__(256) void gemm_h(
    const unsigned short* __restrict__ A,
    const unsigned short* __restrict__ Bt,
    const unsigned short* __restrict__ bias,
    const float* __restrict__ probs,
    unsigned short* __restrict__ outH)
{
    constexpr int K = DIN;
    __shared__ __align__(16) char smem[32768];   // 2 buffers x (8KB A + 8KB B)

    const int t = threadIdx.x;
    const int m0 = blockIdx.x * 128, n0 = blockIdx.y * 128;
    const int wave = t >> 6, lane = t & 63;
    const int wm = wave >> 1, wn = wave & 1;
    const int quad = lane >> 4, l16 = lane & 15;

    f4 acc[4][4];
#pragma unroll
    for (int i = 0; i < 4; i++)
#pragma unroll
        for (int j = 0; j < 4; j++) { acc[i][j][0] = 0.f; acc[i][j][1] = 0.f; acc[i][j][2] = 0.f; acc[i][j][3] = 0.f; }

    const int rA = t >> 2;
    const int cb = (t & 3) * 16;
    const char* pA0 = (const char*)(A + (size_t)(m0 + rA) * K) + cb;
    const char* pA1 = pA0 + (size_t)64 * K * 2;
    const char* pB0 = (const char*)(Bt + (size_t)(n0 + rA) * K) + cb;
    const char* pB1 = pB0 + (size_t)64 * K * 2;

    int aoff[4], boff[4];
#pragma unroll
    for (int i = 0; i < 4; i++) {
        aoff[i] = ((wm * 64 + i * 16 + l16) * 32 + quad * 8) * 2;
        boff[i] = ((wn * 64 + i * 16 + l16) * 32 + quad * 8) * 2;
    }

    auto stage = [&](int buf, int k0) {
        const size_t kb = (size_t)k0 * 2;
        char* s = smem + buf * 16384;
        async16(pA0 + kb, s + t * 16);
        async16(pA1 + kb, s + 4096 + t * 16);
        async16(pB0 + kb, s + 8192 + t * 16);
        async16(pB1 + kb, s + 12288 + t * 16);
    };

    stage(0, 0);
    __syncthreads();        // compiler drains vmcnt(0) before s_barrier
    int cur = 0;
    for (int k0 = 0; k0 < K; k0 += 32) {
        if (k0 + 32 < K) stage(cur ^ 1, k0 + 32);   // overlap next-tile loads with compute
        const char* s = smem + cur * 16384;
        s8 av[4], bv[4];
#pragma unroll
        for (int i = 0; i < 4; i++) av[i] = *(const s8*)(s + aoff[i]);
#pragma unroll
        for (int j = 0; j < 4; j++) bv[j] = *(const s8*)(s + 8192 + boff[j]);
#pragma unroll
        for (int i = 0; i < 4; i++)
#pragma unroll
            for (int j = 0; j < 4; j++)
                acc[i][j] = __builtin_amdgcn_mfma_f32_16x16x32_bf16(av[i], bv[j], acc[i][j], 0, 0, 0);
        __syncthreads();    // one barrier per K-step: drains stage, protects buffer reuse
        cur ^= 1;
    }

#pragma unroll
    for (int i = 0; i < 4; i++) {
        const int gmB = m0 + wm * 64 + i * 16 + quad * 4;
#pragma unroll
        for (int j = 0; j < 4; j++) {
            const int gn = n0 + wn * 64 + j * 16 + l16;
            const int e = gn >> 11;
            const float bval = b2f(bias[gn]);
#pragma unroll
            for (int r = 0; r < 4; r++) {
                const int gm = gmB + r;
                const float pb = probs[(size_t)gm * 8 + e];
                float v = acc[i][j][r] + bval;
                v = fmaxf(v, 0.f) * pb;
                outH[(size_t)gm * NCAT + gn] = f2b(v);
            }
        }
    }
}

// ---------- GEMM2 (split-K): partial[ks][m][n] = Hcat[m, ks-slice] @ w2Tcat[n, ks-slice] ----------
// grid: (rows/128, 8, KS). 2-phase prefetch, one barrier per K-step.
__global__ __launch_bounds__(256) void gemm_out_sk(
    const unsigned short* __restrict__ A,
    const unsigned short* __restrict__ Bt,
    float* __restrict__ partial, int rows)
{
    constexpr int K = NCAT;
    __shared__ __align__(16) char smem[32768];

    const int t = threadIdx.x;
    const int m0 = blockIdx.x * 128, n0 = blockIdx.y * 128;
    const int nks = gridDim.z;
    const int klen = K / nks;
    const int kstart = blockIdx.z * klen;
    const int kend = kstart + klen;
    const int wave = t >> 6, lane = t & 63;
    const int wm = wave >> 1, wn = wave & 1;
    const int quad = lane >> 4, l16 = lane & 15;

    f4 acc[4][4];
#pragma unroll
    for (int i = 0; i < 4; i++)
#pragma unroll
        for (int j = 0; j < 4; j++) { acc[i][j][0] = 0.f; acc[i][j][1] = 0.f; acc[i][j][2] = 0.f; acc[i][j][3] = 0.f; }

    const int rA = t >> 2;
    const int cb = (t & 3) * 16;
    const char* pA0 = (const char*)(A + (size_t)(m0 + rA) * K) + cb;
    const char* pA1 = pA0 + (size_t)64 * K * 2;
    const char* pB0 = (const char*)(Bt + (size_t)(n0 + rA) * K) + cb;
    const char* pB1 = pB0 + (size_t)64 * K * 2;

    int aoff[4], boff[4];
#pragma unroll
    for (int i = 0; i < 4; i++) {
        aoff[i] = ((wm * 64 + i * 16 + l16) * 32 + quad * 8) * 2;
        boff[i] = ((wn * 64 + i * 16 + l16) * 32 + quad * 8) * 2;
    }

    auto stage = [&](int buf, int k0) {
        const size_t kb = (size_t)k0 * 2;
        char* s = smem + buf * 16384;
        async16(pA0 + kb, s + t * 16);
        async16(pA1 + kb, s + 4096 + t * 16);
        async16(pB0 + kb, s + 8192 + t * 16);
        async16(pB1 + kb, s + 12288 + t * 16);
    };

    stage(0, kstart);
    __syncthreads();
    int cur = 0;
    for (int k0 = kstart; k0 < kend; k0 += 32) {
        if (k0 + 32 < kend) stage(cur ^ 1, k0 + 32);
        const char* s = smem + cur * 16384;
        s8 av[4], bv[4];
#pragma unroll
        for (int i = 0; i < 4; i++) av[i] = *(const s8*)(s + aoff[i]);
#pragma unroll
        for (int j = 0; j < 4; j++) bv[j] = *(const s8*)(s + 8192 + boff[j]);
#pragma unroll
        for (int i = 0; i < 4; i++)
#pragma unroll
            for (int j = 0; j < 4; j++)
                acc[i][j] = __builtin_amdgcn_mfma_f32_16x16x32_bf16(av[i], bv[j], acc[i][j], 0, 0, 0);
        __syncthreads();
        cur ^= 1;
    }

    float* pp = partial + (size_t)blockIdx.z * rows * DOUT;
#pragma unroll
    for (int i = 0; i < 4; i++) {
        const int gmB = m0 + wm * 64 + i * 16 + quad * 4;
#pragma unroll
        for (int j = 0; j < 4; j++) {
            const int gn = n0 + wn * 64 + j * 16 + l16;
#pragma unroll
            for (int r = 0; r < 4; r++)
                pp[(size_t)(gmB + r) * DOUT + gn] = acc[i][j][r];
        }
    }
}

// ---------- out finalize: sum split-K partials + probs.b2 bias, dtype-branched write ----------
__global__ __launch_bounds__(256) void out_finalize(
    const float* __restrict__ partial, const unsigned short* __restrict__ b2,
    const float* __restrict__ probs, void* __restrict__ outp, size_t outOff,
    const int* __restrict__ flag, int rows, int nks)
{
    const int idx = blockIdx.x * 256 + threadIdx.x;
    if (idx >= rows * DOUT) return;
    const int m = idx >> 10, n = idx & (DOUT - 1);
    float v = 0.f;
    for (int ks = 0; ks < nks; ks++)
        v += partial[(size_t)ks * rows * DOUT + idx];
    const f4 p0 = *(const f4*)(probs + (size_t)m * 8);
    const f4 p1 = *(const f4*)(probs + (size_t)m * 8 + 4);
    v += p0[0] * b2f(b2[n])            + p0[1] * b2f(b2[DOUT + n])
       + p0[2] * b2f(b2[2 * DOUT + n]) + p0[3] * b2f(b2[3 * DOUT + n])
       + p1[0] * b2f(b2[4 * DOUT + n]) + p1[1] * b2f(b2[5 * DOUT + n])
       + p1[2] * b2f(b2[6 * DOUT + n]) + p1[3] * b2f(b2[7 * DOUT + n]);
    const size_t oi = outOff + ((size_t)m * DOUT) + n;
    if (*flag) ((float*)outp)[oi] = v;
    else       ((unsigned short*)outp)[oi] = f2b(v);
}

extern "C" void kernel_launch(void* const* d_in, const int* in_sizes, int n_in,
                              void* d_out, int out_size, void* d_ws, size_t ws_size,
                              hipStream_t stream)
{
    const void* x   = d_in[0];
    const void* gum = d_in[1];
    const void* gw  = d_in[2];
    const void* gb  = d_in[3];
    const void* w1  = d_in[4];
    const void* b1  = d_in[5];
    const void* w2  = d_in[6];
    const void* b2  = d_in[7];

    char* ws = (char*)d_ws;
    size_t cur = 0;
    auto alloc = [&](size_t bytes) { size_t p = cur; cur = (cur + bytes + 255) & ~(size_t)255; return p; };

    int* flag              = (int*)(ws + alloc(256));
    float* probs           = (float*)(ws + alloc(8192 * 8 * 4));
    float* partials        = (float*)(ws + alloc(256 * 16 * 4));
    unsigned short* xn     = (unsigned short*)(ws + alloc((size_t)B_ROWS * DIN * 2));
    unsigned short* gumn   = (unsigned short*)(ws + alloc((size_t)B_ROWS * 8 * 2));
    unsigned short* gwn    = (unsigned short*)(ws + alloc((size_t)DIN * 8 * 2));
    unsigned short* gbn    = (unsigned short*)(ws + alloc(8 * 2));
    unsigned short* b1n    = (unsigned short*)(ws + alloc((size_t)NE * DH * 2));
    unsigned short* b2n    = (unsigned short*)(ws + alloc((size_t)NE * DOUT * 2));
    unsigned short* w1Tcat = (unsigned short*)(ws + alloc((size_t)NCAT * DIN * 2));   // 32 MiB
    unsigned short* w2Tcat = (unsigned short*)(ws + alloc((size_t)DOUT * NCAT * 2));  // 32 MiB
    const size_t fixed = cur;  // ~81 MB

    // Hcat chunk (R x 16384 bf16) + split-K partials (KS x R x 1024 f32).
    // KS chosen so gemm_out_sk grid = (R/128)*8*KS >= 512 blocks (>=2 blocks/CU).
    int R = B_ROWS, KS = 2;
    for (;;) {
        KS = 8192 / R; if (KS < 2) KS = 2;
        const size_t need = fixed + (size_t)R * (NCAT * 2) + (size_t)KS * R * DOUT * 4;
        if (R <= 256 || need <= ws_size) break;
        R >>= 1;
    }
    unsigned short* Hcat = (unsigned short*)(ws + fixed);
    float* partial = (float*)(ws + fixed + (size_t)R * (NCAT * 2));

    detect_dtype<<<1, 64, 0, stream>>>((const unsigned short*)x, flag);

    normalize_kernel<<<(B_ROWS * DIN + 255) / 256, 256, 0, stream>>>(x, xn, flag, B_ROWS * DIN);
    normalize_kernel<<<(B_ROWS * 8 + 255) / 256, 256, 0, stream>>>(gum, gumn, flag, B_ROWS * 8);
    normalize_kernel<<<(DIN * 8 + 255) / 256, 256, 0, stream>>>(gw, gwn, flag, DIN * 8);
    normalize_kernel<<<1, 256, 0, stream>>>(gb, gbn, flag, 8);
    normalize_kernel<<<(NE * DH + 255) / 256, 256, 0, stream>>>(b1, b1n, flag, NE * DH);
    normalize_kernel<<<(NE * DOUT + 255) / 256, 256, 0, stream>>>(b2, b2n, flag, NE * DOUT);

    gating_kernel<<<256, 256, 0, stream>>>(xn, gumn, gwn, gbn, probs, partials);
    aux_finalize<<<1, 64, 0, stream>>>(partials, d_out, flag);

    transpose_cvt<<<dim3(DH / 64, DIN / 64, NE), dim3(64, 4), 0, stream>>>(
        w1, w1Tcat, DIN, DH, DIN, (size_t)DH * DIN, flag);
    transpose_cvt<<<dim3(DOUT / 64, DH / 64, NE), dim3(64, 4), 0, stream>>>(
        w2, w2Tcat, DH, DOUT, NCAT, (size_t)DH, flag);

    for (int c0 = 0; c0 < B_ROWS; c0 += R) {
        gemm_h<<<dim3(R / 128, NCAT / 128), 256, 0, stream>>>(
            xn + (size_t)c0 * DIN, w1Tcat, b1n, probs + (size_t)c0 * 8, Hcat);
        gemm_out_sk<<<dim3(R / 128, DOUT / 128, KS), 256, 0, stream>>>(
            Hcat, w2Tcat, partial, R);
        out_finalize<<<(R * DOUT) / 256, 256, 0, stream>>>(
            partial, b2n, probs + (size_t)c0 * 8, d_out, (size_t)c0 * DOUT, flag, R, KS);
    }
}